// Round 2
// baseline (366.033 us; speedup 1.0000x reference)
//
#include <hip/hip_runtime.h>

// DevConvLayer: dev[i] = max_j ( A[i,j] ? max((s_i - s_j)*wmax_j, (s_i - s_j)*wmin_j) : 0 )
// broadcast across 3 output channels. s = rowsum(x), wmax/wmin = colwise max/min of W_phi.
// All float tensors are fp32 (per reference; confirmed by 2%-relative threshold math).
// Memory-bound on the 256 MiB int32 adjacency read; roofline ~43 us at 6.3 TB/s.

#define NN 8192

// Kernel 1: build fp32 tables s[j], wmax[j], wmin[j] in workspace.
__global__ __launch_bounds__(256) void prep_kernel(
        const float* __restrict__ x,      // [N,3]
        const float* __restrict__ wphi,   // [3,N]
        float* __restrict__ s,
        float* __restrict__ wmax,
        float* __restrict__ wmin) {
    int j = blockIdx.x * blockDim.x + threadIdx.x;
    if (j < NN) {
        s[j] = x[3 * j + 0] + x[3 * j + 1] + x[3 * j + 2];
        float w0 = wphi[0 * NN + j];
        float w1 = wphi[1 * NN + j];
        float w2 = wphi[2 * NN + j];
        wmax[j] = fmaxf(w0, fmaxf(w1, w2));
        wmin[j] = fminf(w0, fminf(w1, w2));
    }
}

// Kernel 2: one block per row i. 256 threads x 8 iters x int4 = 8192 adjacency
// entries, fully coalesced 32 KB/row stream. Running max starts at 0, which is
// faithful: the reference's candidate set always contains 0 (T[i,i]=0 and
// non-neighbors contribute 0), so the deg>0 select is a no-op.
__global__ __launch_bounds__(256) void row_kernel(
        const int* __restrict__ adj,
        const float* __restrict__ s,
        const float* __restrict__ wmax,
        const float* __restrict__ wmin,
        float* __restrict__ out) {
    const int i = blockIdx.x;
    const int4* __restrict__ arow = (const int4*)(adj + (size_t)i * NN);
    const float4* __restrict__ s4p  = (const float4*)s;
    const float4* __restrict__ wx4p = (const float4*)wmax;
    const float4* __restrict__ wn4p = (const float4*)wmin;

    const float si = s[i];
    float m = 0.0f;

#pragma unroll
    for (int it = 0; it < 8; ++it) {
        int j4 = it * 256 + threadIdx.x;           // int4 index; consecutive across lanes
        int4   a  = arow[j4];
        float4 sv = s4p[j4];
        float4 wx = wx4p[j4];
        float4 wn = wn4p[j4];
        float d, v;
        d = si - sv.x; v = fmaxf(d * wx.x, d * wn.x); if (a.x) m = fmaxf(m, v);
        d = si - sv.y; v = fmaxf(d * wx.y, d * wn.y); if (a.y) m = fmaxf(m, v);
        d = si - sv.z; v = fmaxf(d * wx.z, d * wn.z); if (a.z) m = fmaxf(m, v);
        d = si - sv.w; v = fmaxf(d * wx.w, d * wn.w); if (a.w) m = fmaxf(m, v);
    }

    // Block max-reduction: wave64 shuffle tree (lane-0-rooted reads are always
    // in-range), then LDS across the 4 waves.
#pragma unroll
    for (int off = 32; off > 0; off >>= 1)
        m = fmaxf(m, __shfl_down(m, off, 64));

    __shared__ float red[4];
    int lane = threadIdx.x & 63;
    int wave = threadIdx.x >> 6;
    if (lane == 0) red[wave] = m;
    __syncthreads();
    if (threadIdx.x == 0) {
        m = fmaxf(fmaxf(red[0], red[1]), fmaxf(red[2], red[3]));
        out[3 * i + 0] = m;
        out[3 * i + 1] = m;
        out[3 * i + 2] = m;
    }
}

extern "C" void kernel_launch(void* const* d_in, const int* in_sizes, int n_in,
                              void* d_out, int out_size, void* d_ws, size_t ws_size,
                              hipStream_t stream) {
    const float* x    = (const float*)d_in[0];
    const int*   adj  = (const int*)d_in[1];
    const float* wphi = (const float*)d_in[2];
    // d_in[3] (W_theta) is unused by the reference forward pass.

    float* s    = (float*)d_ws;        // 32 KB
    float* wmax = s + NN;              // 32 KB
    float* wmin = s + 2 * NN;          // 32 KB   (total 96 KB of workspace)

    prep_kernel<<<NN / 256, 256, 0, stream>>>(x, wphi, s, wmax, wmin);
    row_kernel<<<NN, 256, 0, stream>>>(adj, s, wmax, wmin, (float*)d_out);
}

// Round 4
// 348.292 us; speedup vs baseline: 1.0509x; 1.0509x over previous
//
#include <hip/hip_runtime.h>

// DevConvLayer: dev[i] = max_j ( A[i,j] ? max((s_i - s_j)*wmax_j, (s_i - s_j)*wmin_j) : 0 )
// broadcast across 3 output channels. s = rowsum(x), wmax/wmin = colwise max/min of W_phi.
// Memory-bound on the 256 MiB int32 adjacency read; HBM roofline ~43 us at 6.3 TB/s.
// R4: block handles R=8 rows -> table L2 traffic /8 (768->96 MiB); nontemporal adjacency
// via native clang vector type (HIP_vector_type rejected by the builtin).

#define NN 8192
#define R 8

typedef int   iv4 __attribute__((ext_vector_type(4)));
typedef float fv4 __attribute__((ext_vector_type(4)));

// Kernel 1: build fp32 tables s[j], wmax[j], wmin[j] in workspace.
__global__ __launch_bounds__(256) void prep_kernel(
        const float* __restrict__ x,      // [N,3]
        const float* __restrict__ wphi,   // [3,N]
        float* __restrict__ s,
        float* __restrict__ wmax,
        float* __restrict__ wmin) {
    int j = blockIdx.x * blockDim.x + threadIdx.x;
    if (j < NN) {
        s[j] = x[3 * j + 0] + x[3 * j + 1] + x[3 * j + 2];
        float w0 = wphi[0 * NN + j];
        float w1 = wphi[1 * NN + j];
        float w2 = wphi[2 * NN + j];
        wmax[j] = fmaxf(w0, fmaxf(w1, w2));
        wmin[j] = fminf(w0, fminf(w1, w2));
    }
}

// Kernel 2: one block per 8 rows. Per chunk of 1024 j: 3 table float4 loads
// (L2-resident, amortized over 8 rows) + 8 adjacency int4 loads (nontemporal,
// zero-reuse 256 MiB stream). Running max starts at 0 — faithful, since the
// reference's candidate set always contains 0 (T[i,i]=0, non-neighbors give 0),
// making the deg>0 select a no-op.
__global__ __launch_bounds__(256) void row_kernel(
        const int* __restrict__ adj,
        const float* __restrict__ s,
        const float* __restrict__ wmax,
        const float* __restrict__ wmin,
        float* __restrict__ out) {
    const int i0 = blockIdx.x * R;
    const fv4* __restrict__ s4p  = (const fv4*)s;
    const fv4* __restrict__ wx4p = (const fv4*)wmax;
    const fv4* __restrict__ wn4p = (const fv4*)wmin;

    float si[R], m[R];
#pragma unroll
    for (int r = 0; r < R; ++r) { si[r] = s[i0 + r]; m[r] = 0.0f; }

    const iv4* __restrict__ arow = (const iv4*)(adj + (size_t)i0 * NN);

#pragma unroll
    for (int it = 0; it < 8; ++it) {
        const int j4 = it * 256 + (int)threadIdx.x;   // int4 index, coalesced across lanes
        fv4 sv = s4p[j4];
        fv4 wx = wx4p[j4];
        fv4 wn = wn4p[j4];
        iv4 a[R];
#pragma unroll
        for (int r = 0; r < R; ++r)
            a[r] = __builtin_nontemporal_load(&arow[r * (NN / 4) + j4]);
#pragma unroll
        for (int r = 0; r < R; ++r) {
            float d, v;
            d = si[r] - sv.x; v = fmaxf(d * wx.x, d * wn.x); if (a[r].x) m[r] = fmaxf(m[r], v);
            d = si[r] - sv.y; v = fmaxf(d * wx.y, d * wn.y); if (a[r].y) m[r] = fmaxf(m[r], v);
            d = si[r] - sv.z; v = fmaxf(d * wx.z, d * wn.z); if (a[r].z) m[r] = fmaxf(m[r], v);
            d = si[r] - sv.w; v = fmaxf(d * wx.w, d * wn.w); if (a[r].w) m[r] = fmaxf(m[r], v);
        }
    }

    // Block max-reduction: wave64 shuffle per row, then LDS across the 4 waves.
#pragma unroll
    for (int r = 0; r < R; ++r) {
#pragma unroll
        for (int off = 32; off > 0; off >>= 1)
            m[r] = fmaxf(m[r], __shfl_down(m[r], off, 64));
    }

    __shared__ float red[4][R];
    const int lane = threadIdx.x & 63;
    const int wave = threadIdx.x >> 6;
    if (lane == 0) {
#pragma unroll
        for (int r = 0; r < R; ++r) red[wave][r] = m[r];
    }
    __syncthreads();
    if (threadIdx.x < R) {
        const int r = threadIdx.x;
        float v = fmaxf(fmaxf(red[0][r], red[1][r]), fmaxf(red[2][r], red[3][r]));
        const int i = i0 + r;
        out[3 * i + 0] = v;
        out[3 * i + 1] = v;
        out[3 * i + 2] = v;
    }
}

extern "C" void kernel_launch(void* const* d_in, const int* in_sizes, int n_in,
                              void* d_out, int out_size, void* d_ws, size_t ws_size,
                              hipStream_t stream) {
    const float* x    = (const float*)d_in[0];
    const int*   adj  = (const int*)d_in[1];
    const float* wphi = (const float*)d_in[2];
    // d_in[3] (W_theta) is unused by the reference forward pass.

    float* s    = (float*)d_ws;        // 32 KB
    float* wmax = s + NN;              // 32 KB
    float* wmin = s + 2 * NN;          // 32 KB   (total 96 KB of workspace)

    prep_kernel<<<NN / 256, 256, 0, stream>>>(x, wphi, s, wmax, wmin);
    row_kernel<<<NN / R, 256, 0, stream>>>(adj, s, wmax, wmin, (float*)d_out);
}

// Round 5
// 338.800 us; speedup vs baseline: 1.0804x; 1.0280x over previous
//
#include <hip/hip_runtime.h>

// DevConvLayer: dev[i] = max_j ( A[i,j] ? max((s_i - s_j)*wmax_j, (s_i - s_j)*wmin_j) : 0 )
// broadcast across 3 output channels. s = rowsum(x), wmax/wmin = colwise max/min of W_phi.
// Memory-bound on the 256 MiB int32 adjacency read; HBM roofline ~43 us at 6.3 TB/s.
// R5: R=4 rows/block, grid 2048 (8 blocks/CU), launch_bounds(256,6) — ceiling-confirmation
// run: lower VGPR pressure + more waves in flight near the stream tail.

#define NN 8192
#define R 4

typedef int   iv4 __attribute__((ext_vector_type(4)));
typedef float fv4 __attribute__((ext_vector_type(4)));

// Kernel 1: build fp32 tables s[j], wmax[j], wmin[j] in workspace.
__global__ __launch_bounds__(256) void prep_kernel(
        const float* __restrict__ x,      // [N,3]
        const float* __restrict__ wphi,   // [3,N]
        float* __restrict__ s,
        float* __restrict__ wmax,
        float* __restrict__ wmin) {
    int j = blockIdx.x * blockDim.x + threadIdx.x;
    if (j < NN) {
        s[j] = x[3 * j + 0] + x[3 * j + 1] + x[3 * j + 2];
        float w0 = wphi[0 * NN + j];
        float w1 = wphi[1 * NN + j];
        float w2 = wphi[2 * NN + j];
        wmax[j] = fmaxf(w0, fmaxf(w1, w2));
        wmin[j] = fminf(w0, fminf(w1, w2));
    }
}

// Kernel 2: one block per R=4 rows. Per chunk of 1024 j: 3 table float4 loads
// (L2-resident, amortized over 4 rows) + 4 adjacency int4 loads (nontemporal,
// zero-reuse 256 MiB stream). Running max starts at 0 — faithful, since the
// reference's candidate set always contains 0 (T[i,i]=0, non-neighbors give 0),
// making the deg>0 select a no-op.
__global__ __launch_bounds__(256, 6) void row_kernel(
        const int* __restrict__ adj,
        const float* __restrict__ s,
        const float* __restrict__ wmax,
        const float* __restrict__ wmin,
        float* __restrict__ out) {
    const int i0 = blockIdx.x * R;
    const fv4* __restrict__ s4p  = (const fv4*)s;
    const fv4* __restrict__ wx4p = (const fv4*)wmax;
    const fv4* __restrict__ wn4p = (const fv4*)wmin;

    float si[R], m[R];
#pragma unroll
    for (int r = 0; r < R; ++r) { si[r] = s[i0 + r]; m[r] = 0.0f; }

    const iv4* __restrict__ arow = (const iv4*)(adj + (size_t)i0 * NN);

#pragma unroll
    for (int it = 0; it < 8; ++it) {
        const int j4 = it * 256 + (int)threadIdx.x;   // int4 index, coalesced across lanes
        fv4 sv = s4p[j4];
        fv4 wx = wx4p[j4];
        fv4 wn = wn4p[j4];
        iv4 a[R];
#pragma unroll
        for (int r = 0; r < R; ++r)
            a[r] = __builtin_nontemporal_load(&arow[r * (NN / 4) + j4]);
#pragma unroll
        for (int r = 0; r < R; ++r) {
            float d, v;
            d = si[r] - sv.x; v = fmaxf(d * wx.x, d * wn.x); if (a[r].x) m[r] = fmaxf(m[r], v);
            d = si[r] - sv.y; v = fmaxf(d * wx.y, d * wn.y); if (a[r].y) m[r] = fmaxf(m[r], v);
            d = si[r] - sv.z; v = fmaxf(d * wx.z, d * wn.z); if (a[r].z) m[r] = fmaxf(m[r], v);
            d = si[r] - sv.w; v = fmaxf(d * wx.w, d * wn.w); if (a[r].w) m[r] = fmaxf(m[r], v);
        }
    }

    // Block max-reduction: wave64 shuffle per row, then LDS across the 4 waves.
#pragma unroll
    for (int r = 0; r < R; ++r) {
#pragma unroll
        for (int off = 32; off > 0; off >>= 1)
            m[r] = fmaxf(m[r], __shfl_down(m[r], off, 64));
    }

    __shared__ float red[4][R];
    const int lane = threadIdx.x & 63;
    const int wave = threadIdx.x >> 6;
    if (lane == 0) {
#pragma unroll
        for (int r = 0; r < R; ++r) red[wave][r] = m[r];
    }
    __syncthreads();
    if (threadIdx.x < R) {
        const int r = threadIdx.x;
        float v = fmaxf(fmaxf(red[0][r], red[1][r]), fmaxf(red[2][r], red[3][r]));
        const int i = i0 + r;
        out[3 * i + 0] = v;
        out[3 * i + 1] = v;
        out[3 * i + 2] = v;
    }
}

extern "C" void kernel_launch(void* const* d_in, const int* in_sizes, int n_in,
                              void* d_out, int out_size, void* d_ws, size_t ws_size,
                              hipStream_t stream) {
    const float* x    = (const float*)d_in[0];
    const int*   adj  = (const int*)d_in[1];
    const float* wphi = (const float*)d_in[2];
    // d_in[3] (W_theta) is unused by the reference forward pass.

    float* s    = (float*)d_ws;        // 32 KB
    float* wmax = s + NN;              // 32 KB
    float* wmin = s + 2 * NN;          // 32 KB   (total 96 KB of workspace)

    prep_kernel<<<NN / 256, 256, 0, stream>>>(x, wphi, s, wmax, wmin);
    row_kernel<<<NN / R, 256, 0, stream>>>(adj, s, wmax, wmin, (float*)d_out);
}

// Round 6
// 338.405 us; speedup vs baseline: 1.0816x; 1.0012x over previous
//
#include <hip/hip_runtime.h>

// DevConvLayer: dev[i] = max_j ( A[i,j] ? max((s_i - s_j)*wmax_j, (s_i - s_j)*wmin_j) : 0 )
// broadcast across 3 output channels. s = rowsum(x), wmax/wmin = colwise max/min of W_phi.
// Memory-bound on the 256 MiB int32 adjacency read; HBM roofline ~43 us at 6.3 TB/s.
// R6: R=4 + __launch_bounds__(256,8) -> 32 waves/CU (max occupancy; ~58 VGPR fits the
// 64-reg budget); adjacency (HBM) loads issued before table (L2) loads.
// VALU model: ~14% busy at full occupancy — pure stream, only latency hiding matters.

#define NN 8192
#define R 4

typedef int   iv4 __attribute__((ext_vector_type(4)));
typedef float fv4 __attribute__((ext_vector_type(4)));

// Kernel 1: build fp32 tables s[j], wmax[j], wmin[j] in workspace.
__global__ __launch_bounds__(256) void prep_kernel(
        const float* __restrict__ x,      // [N,3]
        const float* __restrict__ wphi,   // [3,N]
        float* __restrict__ s,
        float* __restrict__ wmax,
        float* __restrict__ wmin) {
    int j = blockIdx.x * blockDim.x + threadIdx.x;
    if (j < NN) {
        s[j] = x[3 * j + 0] + x[3 * j + 1] + x[3 * j + 2];
        float w0 = wphi[0 * NN + j];
        float w1 = wphi[1 * NN + j];
        float w2 = wphi[2 * NN + j];
        wmax[j] = fmaxf(w0, fmaxf(w1, w2));
        wmin[j] = fminf(w0, fminf(w1, w2));
    }
}

// Kernel 2: one block per R=4 rows. Per chunk of 1024 j: 4 adjacency int4 loads
// (nontemporal, zero-reuse 256 MiB stream, issued first) + 3 table float4 loads
// (L2-resident). Running max starts at 0 — faithful, since the reference's
// candidate set always contains 0 (T[i,i]=0, non-neighbors give 0), making the
// deg>0 select a no-op.
__global__ __launch_bounds__(256, 8) void row_kernel(
        const int* __restrict__ adj,
        const float* __restrict__ s,
        const float* __restrict__ wmax,
        const float* __restrict__ wmin,
        float* __restrict__ out) {
    const int i0 = blockIdx.x * R;
    const fv4* __restrict__ s4p  = (const fv4*)s;
    const fv4* __restrict__ wx4p = (const fv4*)wmax;
    const fv4* __restrict__ wn4p = (const fv4*)wmin;

    float si[R], m[R];
#pragma unroll
    for (int r = 0; r < R; ++r) { si[r] = s[i0 + r]; m[r] = 0.0f; }

    const iv4* __restrict__ arow = (const iv4*)(adj + (size_t)i0 * NN);

#pragma unroll
    for (int it = 0; it < 8; ++it) {
        const int j4 = it * 256 + (int)threadIdx.x;   // int4 index, coalesced across lanes
        iv4 a[R];
#pragma unroll
        for (int r = 0; r < R; ++r)
            a[r] = __builtin_nontemporal_load(&arow[r * (NN / 4) + j4]);
        fv4 sv = s4p[j4];
        fv4 wx = wx4p[j4];
        fv4 wn = wn4p[j4];
#pragma unroll
        for (int r = 0; r < R; ++r) {
            float d, v;
            d = si[r] - sv.x; v = fmaxf(d * wx.x, d * wn.x); if (a[r].x) m[r] = fmaxf(m[r], v);
            d = si[r] - sv.y; v = fmaxf(d * wx.y, d * wn.y); if (a[r].y) m[r] = fmaxf(m[r], v);
            d = si[r] - sv.z; v = fmaxf(d * wx.z, d * wn.z); if (a[r].z) m[r] = fmaxf(m[r], v);
            d = si[r] - sv.w; v = fmaxf(d * wx.w, d * wn.w); if (a[r].w) m[r] = fmaxf(m[r], v);
        }
    }

    // Block max-reduction: wave64 shuffle per row, then LDS across the 4 waves.
#pragma unroll
    for (int r = 0; r < R; ++r) {
#pragma unroll
        for (int off = 32; off > 0; off >>= 1)
            m[r] = fmaxf(m[r], __shfl_down(m[r], off, 64));
    }

    __shared__ float red[4][R];
    const int lane = threadIdx.x & 63;
    const int wave = threadIdx.x >> 6;
    if (lane == 0) {
#pragma unroll
        for (int r = 0; r < R; ++r) red[wave][r] = m[r];
    }
    __syncthreads();
    if (threadIdx.x < R) {
        const int r = threadIdx.x;
        float v = fmaxf(fmaxf(red[0][r], red[1][r]), fmaxf(red[2][r], red[3][r]));
        const int i = i0 + r;
        out[3 * i + 0] = v;
        out[3 * i + 1] = v;
        out[3 * i + 2] = v;
    }
}

extern "C" void kernel_launch(void* const* d_in, const int* in_sizes, int n_in,
                              void* d_out, int out_size, void* d_ws, size_t ws_size,
                              hipStream_t stream) {
    const float* x    = (const float*)d_in[0];
    const int*   adj  = (const int*)d_in[1];
    const float* wphi = (const float*)d_in[2];
    // d_in[3] (W_theta) is unused by the reference forward pass.

    float* s    = (float*)d_ws;        // 32 KB
    float* wmax = s + NN;              // 32 KB
    float* wmin = s + 2 * NN;          // 32 KB   (total 96 KB of workspace)

    prep_kernel<<<NN / 256, 256, 0, stream>>>(x, wphi, s, wmax, wmin);
    row_kernel<<<NN / R, 256, 0, stream>>>(adj, s, wmax, wmin, (float*)d_out);
}